// Round 8
// baseline (249.315 us; speedup 1.0000x reference)
//
#include <hip/hip_runtime.h>

#define ALPHA 0.1f
#define NUM_CLASSES 10

typedef __attribute__((ext_vector_type(8))) short bf16x8;
typedef __attribute__((ext_vector_type(4))) float f32x4;

// ---------------------------------------------------------------------------
// ws layout (bytes):
//   loss   @ 0   : float[1]
//   counts @ 4   : uint[100]
//   ticket @ 448 : uint[1]
// (zeroed each launch via hipMemsetAsync, 512 B)
//
// ROUND 18: R17 ping-pong stream (proven 70us, 64 VGPR, zero spill) +
// R16's last-block fusion retried on a (hopefully) warm container.
//   R16's "regression" was clock-degradation (all rate counters uniformly
//   x2.6, FETCH identical, VGPR 64): structurally it matched R17.  Even
//   cold, its e2e-minus-dist gap was 56us vs the 3-node graph's stable
//   80us -> fusion shrinks the inter-node overhead.  This round = R17
//   main loop byte-for-byte + fused finalize tail (ticket + last-block
//   greedy), 2 graph nodes (memset + dist).
//   Hard rules (R11/R14): launch_bounds(512,4) only, persistent reg set
//   unchanged; WRITE_SIZE jump = spill alarm.
// ---------------------------------------------------------------------------

__device__ __forceinline__ unsigned pack2(float a, float b) {
    // bf16(a) lo16 | bf16(b) hi16 (truncation -> exact Dekker hi split)
    return (__float_as_uint(b) & 0xFFFF0000u) | (__float_as_uint(a) >> 16);
}
__device__ __forceinline__ float truncbf(float a) {
    return __uint_as_float(__float_as_uint(a) & 0xFFFF0000u);
}

// stage: convert this wave's prefetched 16-pt subtile into buffer BUF slot
// SUB; write x2; reload pv with tile TNEXT's rows (if valid).
#define STAGE_HALF(BUF, SUB, TNEXT)                                           \
    {                                                                         \
        float4 v0 = pv0, v1 = pv1, v2 = pv2, v3 = pv3;                        \
        if ((TNEXT) < NT) {                                                   \
            const int row_ = (TNEXT) * 128 + w * 16 + r;                      \
            const float4* X_ = (const float4*)(x + (size_t)row_ * 64);        \
            pv0 = X_[q * 2]; pv1 = X_[q * 2 + 1];                             \
            pv2 = X_[8 + q * 2]; pv3 = X_[9 + q * 2];                         \
        }                                                                     \
        float p = v0.x * v0.x;                                                \
        p = fmaf(v0.y, v0.y, p); p = fmaf(v0.z, v0.z, p); p = fmaf(v0.w, v0.w, p); \
        p = fmaf(v1.x, v1.x, p); p = fmaf(v1.y, v1.y, p); p = fmaf(v1.z, v1.z, p); p = fmaf(v1.w, v1.w, p); \
        p = fmaf(v2.x, v2.x, p); p = fmaf(v2.y, v2.y, p); p = fmaf(v2.z, v2.z, p); p = fmaf(v2.w, v2.w, p); \
        p = fmaf(v3.x, v3.x, p); p = fmaf(v3.y, v3.y, p); p = fmaf(v3.z, v3.z, p); p = fmaf(v3.w, v3.w, p); \
        p += __shfl_xor(p, 16);                                               \
        p += __shfl_xor(p, 32);                                               \
        if (q == 0) x2s[BUF][(SUB) * 16 + r] = p;                             \
        union { bf16x8 v; uint4 u4; unsigned u[4]; } h0, h1, l0, l1;          \
        h0.u[0] = pack2(v0.x, v0.y); h0.u[1] = pack2(v0.z, v0.w);             \
        h0.u[2] = pack2(v1.x, v1.y); h0.u[3] = pack2(v1.z, v1.w);             \
        h1.u[0] = pack2(v2.x, v2.y); h1.u[1] = pack2(v2.z, v2.w);             \
        h1.u[2] = pack2(v3.x, v3.y); h1.u[3] = pack2(v3.z, v3.w);             \
        l0.u[0] = pack2(v0.x - truncbf(v0.x), v0.y - truncbf(v0.y));          \
        l0.u[1] = pack2(v0.z - truncbf(v0.z), v0.w - truncbf(v0.w));          \
        l0.u[2] = pack2(v1.x - truncbf(v1.x), v1.y - truncbf(v1.y));          \
        l0.u[3] = pack2(v1.z - truncbf(v1.z), v1.w - truncbf(v1.w));          \
        l1.u[0] = pack2(v2.x - truncbf(v2.x), v2.y - truncbf(v2.y));          \
        l1.u[1] = pack2(v2.z - truncbf(v2.z), v2.w - truncbf(v2.w));          \
        l1.u[2] = pack2(v3.x - truncbf(v3.x), v3.y - truncbf(v3.y));          \
        l1.u[3] = pack2(v3.z - truncbf(v3.z), v3.w - truncbf(v3.w));          \
        *(uint4*)(bstage + ((((BUF) * 16 + (SUB) * 4 + 0) * 64 + lane) << 4)) = h0.u4; \
        *(uint4*)(bstage + ((((BUF) * 16 + (SUB) * 4 + 1) * 64 + lane) << 4)) = h1.u4; \
        *(uint4*)(bstage + ((((BUF) * 16 + (SUB) * 4 + 2) * 64 + lane) << 4)) = l0.u4; \
        *(uint4*)(bstage + ((((BUF) * 16 + (SUB) * 4 + 3) * 64 + lane) << 4)) = l1.u4; \
    }

// compute: all 8 waves, 4 subtiles of buffer BUF -> comb[BUF].
#define COMPUTE_HALF(BUF)                                                     \
    _Pragma("unroll")                                                         \
    for (int pt = 0; pt < 4; ++pt) {                                          \
        union { uint4 u4; bf16x8 v; } b0, b1, b2, b3;                         \
        b0.u4 = *(const uint4*)(bstage + ((((BUF) * 16 + pt * 4 + 0) * 64 + lane) << 4)); \
        b1.u4 = *(const uint4*)(bstage + ((((BUF) * 16 + pt * 4 + 1) * 64 + lane) << 4)); \
        b2.u4 = *(const uint4*)(bstage + ((((BUF) * 16 + pt * 4 + 2) * 64 + lane) << 4)); \
        b3.u4 = *(const uint4*)(bstage + ((((BUF) * 16 + pt * 4 + 3) * 64 + lane) << 4)); \
        const float x2p = x2s[BUF][pt * 16 + r];                              \
        f32x4 acc[2];                                                         \
        _Pragma("unroll")                                                     \
        for (int ct = 0; ct < 2; ++ct) {                                      \
            f32x4 a;                                                          \
            a[0] = x2p + c2r1[ct][0]; a[1] = x2p + c2r1[ct][1];               \
            a[2] = x2p + c2r1[ct][2]; a[3] = x2p + c2r1[ct][3];               \
            a = __builtin_amdgcn_mfma_f32_16x16x32_bf16(af[ct][0], b0.v, a, 0, 0, 0); \
            a = __builtin_amdgcn_mfma_f32_16x16x32_bf16(af[ct][1], b1.v, a, 0, 0, 0); \
            a = __builtin_amdgcn_mfma_f32_16x16x32_bf16(af[ct][2], b0.v, a, 0, 0, 0); \
            a = __builtin_amdgcn_mfma_f32_16x16x32_bf16(af[ct][3], b1.v, a, 0, 0, 0); \
            a = __builtin_amdgcn_mfma_f32_16x16x32_bf16(af[ct][0], b2.v, a, 0, 0, 0); \
            a = __builtin_amdgcn_mfma_f32_16x16x32_bf16(af[ct][1], b3.v, a, 0, 0, 0); \
            acc[ct] = a;                                                      \
        }                                                                     \
        float swe = 0.f, swdu = 0.f;                                          \
        unsigned best = 0xFFFFFFFFu;                                          \
        _Pragma("unroll")                                                     \
        for (int ct = 0; ct < 2; ++ct) {                                      \
            _Pragma("unroll")                                                 \
            for (int reg = 0; reg < 4; ++reg) {                               \
                const float u = acc[ct][reg];                                 \
                const unsigned kid = (unsigned)(w * 32 + ct * 16 + q * 4 + reg); \
                best = min(best, (__float_as_uint(u) & 0xFFFFFF00u) | kid);   \
                float wg = exp2f(-ALPHA * __log2f(u));                        \
                swe += wg;                                                    \
                swdu = fmaf(wg, u, swdu);                                     \
            }                                                                 \
        }                                                                     \
        swe += __shfl_xor(swe, 16); swe += __shfl_xor(swe, 32);               \
        swdu += __shfl_xor(swdu, 16); swdu += __shfl_xor(swdu, 32);           \
        best = min(best, (unsigned)__shfl_xor((int)best, 16));                \
        best = min(best, (unsigned)__shfl_xor((int)best, 32));                \
        if (q == 0) {                                                         \
            comb_swe[BUF][w][pt * 16 + r]  = swe;                             \
            comb_swd[BUF][w][pt * 16 + r]  = swdu;                            \
            comb_best[BUF][w][pt * 16 + r] = best;                            \
        }                                                                     \
    }

// combine: one wave (64 lanes = 64 points of the half) folds the 8 groups.
#define COMBINE_HALF(BUF, YL)                                                 \
    {                                                                         \
        float SWE = comb_swe[BUF][0][lane], SWD = comb_swd[BUF][0][lane];     \
        unsigned BEST = comb_best[BUF][0][lane];                              \
        _Pragma("unroll")                                                     \
        for (int g = 1; g < 8; ++g) {                                         \
            SWE += comb_swe[BUF][g][lane];                                    \
            SWD += comb_swd[BUF][g][lane];                                    \
            BEST = min(BEST, comb_best[BUF][g][lane]);                        \
        }                                                                     \
        loss_local += SWD / SWE - 1.f;                                        \
        const unsigned bk = BEST & 0xFFu;                                     \
        if (bk < NUM_CLASSES) {                                               \
            atomicAdd(&counts_l[bk * NUM_CLASSES + (YL)], 1u);                \
        }                                                                     \
    }

// 512 threads = 8 waves.  Wave w owns centers [w*32, w*32+32) (M dim) and
// stages points [t*128 + w*16, +16): quad0 (w<4) = even halves (pts 0-63),
// quad1 = odd halves (pts 64-127).  Lane: r = l&15, q = l>>4.
__global__ __launch_bounds__(512, 4) void dist_kernel(
    const float* __restrict__ x,
    const int*   __restrict__ y,
    const float* __restrict__ centers,
    float* __restrict__ loss_acc,
    unsigned int* __restrict__ counts,
    unsigned int* __restrict__ ticket,
    float* __restrict__ out,
    int NT, int NPTS)
{
    __shared__ __align__(16) char bstage[2 * 16 * 64 * 16];   // 32 KB, 2 bufs
    __shared__ float x2s[2][64];
    __shared__ float c2s[256];
    __shared__ float    comb_swe[2][8][64];    // 4 KB
    __shared__ float    comb_swd[2][8][64];    // 4 KB
    __shared__ unsigned comb_best[2][8][64];   // 4 KB
    __shared__ unsigned counts_l[100];
    __shared__ float    fin_cs[100];
    __shared__ float    fin_ls;
    __shared__ unsigned fin_flag;

    const int tid  = threadIdx.x;
    const int w    = tid >> 6;
    const int lane = tid & 63;
    const int q    = lane >> 4;
    const int r    = lane & 15;

    if (tid < 100) counts_l[tid] = 0u;

    // ---- startup: center norms (one center per thread) ----
    if (tid < 256) {
        const float4* crow = (const float4*)(centers + tid * 64);
        float s = 0.f;
#pragma unroll
        for (int j = 0; j < 16; ++j) {
            float4 v = crow[j];
            s = fmaf(v.x, v.x, s); s = fmaf(v.y, v.y, s);
            s = fmaf(v.z, v.z, s); s = fmaf(v.w, v.w, s);
        }
        c2s[tid] = s;
    }

    // ---- startup: this wave's center A-frags, PRE-SCALED by -2 ----
    bf16x8 af[2][4];
#pragma unroll
    for (int ct = 0; ct < 2; ++ct) {
        const int row = w * 32 + ct * 16 + r;
        const float4* C = (const float4*)(centers + (size_t)row * 64);
        float4 v0 = C[q * 2], v1 = C[q * 2 + 1];
        float4 v2 = C[8 + q * 2], v3 = C[9 + q * 2];
        float4 m0 = make_float4(-2.f * v0.x, -2.f * v0.y, -2.f * v0.z, -2.f * v0.w);
        float4 m1 = make_float4(-2.f * v1.x, -2.f * v1.y, -2.f * v1.z, -2.f * v1.w);
        float4 m2 = make_float4(-2.f * v2.x, -2.f * v2.y, -2.f * v2.z, -2.f * v2.w);
        float4 m3 = make_float4(-2.f * v3.x, -2.f * v3.y, -2.f * v3.z, -2.f * v3.w);
        union { bf16x8 v; unsigned u[4]; } h0, h1, l0, l1;
        h0.u[0] = pack2(m0.x, m0.y); h0.u[1] = pack2(m0.z, m0.w);
        h0.u[2] = pack2(m1.x, m1.y); h0.u[3] = pack2(m1.z, m1.w);
        h1.u[0] = pack2(m2.x, m2.y); h1.u[1] = pack2(m2.z, m2.w);
        h1.u[2] = pack2(m3.x, m3.y); h1.u[3] = pack2(m3.z, m3.w);
        l0.u[0] = pack2(m0.x - truncbf(m0.x), m0.y - truncbf(m0.y));
        l0.u[1] = pack2(m0.z - truncbf(m0.z), m0.w - truncbf(m0.w));
        l0.u[2] = pack2(m1.x - truncbf(m1.x), m1.y - truncbf(m1.y));
        l0.u[3] = pack2(m1.z - truncbf(m1.z), m1.w - truncbf(m1.w));
        l1.u[0] = pack2(m2.x - truncbf(m2.x), m2.y - truncbf(m2.y));
        l1.u[1] = pack2(m2.z - truncbf(m2.z), m2.w - truncbf(m2.w));
        l1.u[2] = pack2(m3.x - truncbf(m3.x), m3.y - truncbf(m3.y));
        l1.u[3] = pack2(m3.z - truncbf(m3.z), m3.w - truncbf(m3.w));
        af[ct][0] = h0.v; af[ct][1] = h1.v; af[ct][2] = l0.v; af[ct][3] = l1.v;
    }

    // ---- prefetch tile t0's x rows (every wave: its own 16-pt subtile) ----
    const int G  = gridDim.x;
    const int t0 = blockIdx.x;
    float4 pv0, pv1, pv2, pv3;
    {
        const int row = t0 * 128 + w * 16 + r;
        const float4* X = (const float4*)(x + (size_t)row * 64);
        pv0 = X[q * 2]; pv1 = X[q * 2 + 1];
        pv2 = X[8 + q * 2]; pv3 = X[9 + q * 2];
    }

    // ---- prologue: quad0 stages half(t0,0) into buf0 ----
    if (w < 4) STAGE_HALF(0, w, t0 + G);

    __syncthreads();   // c2s + buf0 + x2s[0] + counts_l visible

    // this lane's 8 center norms + 1: u = (x2 + c2 + 1) + (-2 x.c)
    float c2r1[2][4];
#pragma unroll
    for (int ct = 0; ct < 2; ++ct) {
        float4 v = *(const float4*)(c2s + w * 32 + ct * 16 + q * 4);
        c2r1[ct][0] = v.x + 1.f; c2r1[ct][1] = v.y + 1.f;
        c2r1[ct][2] = v.z + 1.f; c2r1[ct][3] = v.w + 1.f;
    }

    float loss_local = 0.f;
    int have_prev = 0;
    int t = t0;
    for (; t < NT; t += G) {
        // ---- body A: stage half(t,1)[quad1] || compute half(t,0)[all]
        //              || combine half(t-G,1)[wave 0] ----
        int yA = 0;
        if (w == 0 && have_prev) yA = y[(t - G) * 128 + 64 + lane];
        if (w >= 4) STAGE_HALF(1, w - 4, t + G);
        COMPUTE_HALF(0);
        if (w == 0 && have_prev) COMBINE_HALF(1, yA);
        __syncthreads();   // buf1+x2s[1] staged; comb[0] full; comb[1] free

        // ---- body B: stage half(t+G,0)[quad0] || compute half(t,1)[all]
        //              || combine half(t,0)[wave 7] ----
        int yB = 0;
        if (w == 7) yB = y[t * 128 + lane];
        if (w < 4 && (t + G) < NT) STAGE_HALF(0, w, t + 2 * G);
        COMPUTE_HALF(1);
        if (w == 7) COMBINE_HALF(0, yB);
        __syncthreads();   // buf0(next) staged; comb[1] full; comb[0] free

        have_prev = 1;
    }

    // ---- drain: combine the final odd half (t_last,1) ----
    if (w == 0) {
        const int tl = t - G;
        const int yD = y[tl * 128 + 64 + lane];
        COMBINE_HALF(1, yD);
    }

    // loss lives on waves 0 and 7 only
    if (w == 0 || w == 7) {
        float v = loss_local;
#pragma unroll
        for (int o = 32; o > 0; o >>= 1) v += __shfl_down(v, o);
        if (lane == 0) atomicAdd(loss_acc, v);
    }

    __syncthreads();
    if (tid < 100) {
        const unsigned c = counts_l[tid];
        if (c) atomicAdd(&counts[tid], c);
    }
    __threadfence();
    __syncthreads();   // this block's device atomics are issued & fenced

    // ---- last-block finalize (greedy mirror of the reference) ----
    if (tid == 0) {
        fin_flag = (atomicAdd(ticket, 1u) == (unsigned)(gridDim.x - 1)) ? 1u : 0u;
    }
    __syncthreads();
    if (fin_flag) {
        if (tid < 100) fin_cs[tid] = (float)atomicAdd(&counts[tid], 0u);
        if (tid == 100) fin_ls = atomicAdd(loss_acc, 0.f);
        __syncthreads();
        if (tid == 0) {
            bool used[NUM_CLASSES];
            for (int i = 0; i < NUM_CLASSES; ++i) used[i] = false;
            float correct = 0.f;
            for (int i = 0; i < NUM_CLASSES; ++i) {
                const float* ci = fin_cs + i * NUM_CLASSES;
                float rowsum = 0.f;
                for (int j = 0; j < NUM_CLASSES; ++j) rowsum += ci[j];
                bool has_points = rowsum > 0.f;

                int label = 0;
                float mx = ci[0];
                for (int j = 1; j < NUM_CLASSES; ++j)
                    if (ci[j] > mx) { mx = ci[j]; label = j; }

                if (used[label]) {
                    float mm = used[0] ? 0.f : ci[0];
                    int l2 = 0;
                    for (int j = 1; j < NUM_CLASSES; ++j) {
                        float v = used[j] ? 0.f : ci[j];
                        if (v > mm) { mm = v; l2 = j; }
                    }
                    label = l2;
                }

                if (has_points) {
                    correct += ci[label];
                    used[label] = true;
                }
            }
            out[0] = fin_ls;
            out[1] = correct / (float)NPTS;
        }
    }
}

// ---------------------------------------------------------------------------

extern "C" void kernel_launch(void* const* d_in, const int* in_sizes, int n_in,
                              void* d_out, int out_size, void* d_ws, size_t ws_size,
                              hipStream_t stream)
{
    const float* x       = (const float*)d_in[0];
    const int*   y       = (const int*)d_in[1];
    const float* centers = (const float*)d_in[2];
    float* out = (float*)d_out;

    const int N  = in_sizes[0] / 64;  // D = 64
    const int NT = N / 128;           // 128-point tiles

    float* loss          = (float*)d_ws;                         // 4 B
    unsigned int* counts = (unsigned int*)((char*)d_ws + 4);     // 400 B
    unsigned int* ticket = (unsigned int*)((char*)d_ws + 448);   // 4 B

    hipMemsetAsync(d_ws, 0, 512, stream);

    int grid = 1024;   // NT=2048 -> 2 tiles/block; LDS ~48KB -> 3 blocks/CU
    if (grid > NT) grid = NT;
    dist_kernel<<<grid, 512, 0, stream>>>(x, y, centers, loss, counts, ticket,
                                          out, NT, N);
}

// Round 9
// 151.024 us; speedup vs baseline: 1.6508x; 1.6508x over previous
//
#include <hip/hip_runtime.h>

#define ALPHA 0.1f
#define NUM_CLASSES 10

typedef __attribute__((ext_vector_type(8))) short bf16x8;
typedef __attribute__((ext_vector_type(4))) float f32x4;

// ---------------------------------------------------------------------------
// ws layout (bytes):
//   loss  @ 0   : float[1]
//   counts@ 4   : uint[100]
// (zeroed each launch via hipMemsetAsync)
//
// ROUND 19: back to the 3-node graph (R16/R18 fusion reproducibly +100us
// e2e on warm containers -- per-block __threadfence/L2-writeback suspected;
// rejected 2-for-2).  Base = R17 ping-pong skeleton (proven 70us dist,
// 150.5us e2e).  Added: the R14 latency levers, now fairly tested under
// launch_bounds(512,4) (R14's failure was its (512,6) 40-VGPR squeeze;
// with LDS capping us at 3 blocks/CU = 6 waves/EU, VGPR up to ~85 is free):
//  i.  MFMA chains split 3+3 by k-half (accA preloaded x2+c2+1, accB zero,
//      merged with 4 adds): dep depth 6 -> 3, 4 independent chains/pt.
//  ii. one-round gather reductions (3 parallel __shfl + 2-deep tree) for
//      x2 / swe / swdu / best (was 2 serial shfl_xor rounds each).
//  iii.tree-shaped epilogue sums (parallel trans, independent fma trees).
// Numerics: identical to R14's stream, which PASSED (absmax 0).
// Spill alarm: WRITE_SIZE must stay ~154KB; VGPR expected 72-88.
// ---------------------------------------------------------------------------

__device__ __forceinline__ unsigned pack2(float a, float b) {
    // bf16(a) lo16 | bf16(b) hi16 (truncation -> exact Dekker hi split)
    return (__float_as_uint(b) & 0xFFFF0000u) | (__float_as_uint(a) >> 16);
}
__device__ __forceinline__ float truncbf(float a) {
    return __uint_as_float(__float_as_uint(a) & 0xFFFF0000u);
}
__device__ __forceinline__ float gsum4(float v, int s1, int s2, int s3) {
    // valid in lanes 0-15 only (gather from r+16, r+32, r+48)
    const float a = __shfl(v, s1);
    const float b = __shfl(v, s2);
    const float c = __shfl(v, s3);
    return (v + a) + (b + c);
}
__device__ __forceinline__ unsigned gmin4(unsigned v, int s1, int s2, int s3) {
    const unsigned a = (unsigned)__shfl((int)v, s1);
    const unsigned b = (unsigned)__shfl((int)v, s2);
    const unsigned c = (unsigned)__shfl((int)v, s3);
    return min(min(v, a), min(b, c));
}

// stage: convert this wave's prefetched 16-pt subtile into buffer BUF slot
// SUB; write x2; reload pv with tile TNEXT's rows (if valid).
#define STAGE_HALF(BUF, SUB, TNEXT)                                           \
    {                                                                         \
        float4 v0 = pv0, v1 = pv1, v2 = pv2, v3 = pv3;                        \
        if ((TNEXT) < NT) {                                                   \
            const int row_ = (TNEXT) * 128 + w * 16 + r;                      \
            const float4* X_ = (const float4*)(x + (size_t)row_ * 64);        \
            pv0 = X_[q * 2]; pv1 = X_[q * 2 + 1];                             \
            pv2 = X_[8 + q * 2]; pv3 = X_[9 + q * 2];                         \
        }                                                                     \
        float p = v0.x * v0.x;                                                \
        p = fmaf(v0.y, v0.y, p); p = fmaf(v0.z, v0.z, p); p = fmaf(v0.w, v0.w, p); \
        p = fmaf(v1.x, v1.x, p); p = fmaf(v1.y, v1.y, p); p = fmaf(v1.z, v1.z, p); p = fmaf(v1.w, v1.w, p); \
        p = fmaf(v2.x, v2.x, p); p = fmaf(v2.y, v2.y, p); p = fmaf(v2.z, v2.z, p); p = fmaf(v2.w, v2.w, p); \
        p = fmaf(v3.x, v3.x, p); p = fmaf(v3.y, v3.y, p); p = fmaf(v3.z, v3.z, p); p = fmaf(v3.w, v3.w, p); \
        p = gsum4(p, s1, s2, s3);                                             \
        if (q == 0) x2s[BUF][(SUB) * 16 + r] = p;                             \
        union { bf16x8 v; uint4 u4; unsigned u[4]; } h0, h1, l0, l1;          \
        h0.u[0] = pack2(v0.x, v0.y); h0.u[1] = pack2(v0.z, v0.w);             \
        h0.u[2] = pack2(v1.x, v1.y); h0.u[3] = pack2(v1.z, v1.w);             \
        h1.u[0] = pack2(v2.x, v2.y); h1.u[1] = pack2(v2.z, v2.w);             \
        h1.u[2] = pack2(v3.x, v3.y); h1.u[3] = pack2(v3.z, v3.w);             \
        l0.u[0] = pack2(v0.x - truncbf(v0.x), v0.y - truncbf(v0.y));          \
        l0.u[1] = pack2(v0.z - truncbf(v0.z), v0.w - truncbf(v0.w));          \
        l0.u[2] = pack2(v1.x - truncbf(v1.x), v1.y - truncbf(v1.y));          \
        l0.u[3] = pack2(v1.z - truncbf(v1.z), v1.w - truncbf(v1.w));          \
        l1.u[0] = pack2(v2.x - truncbf(v2.x), v2.y - truncbf(v2.y));          \
        l1.u[1] = pack2(v2.z - truncbf(v2.z), v2.w - truncbf(v2.w));          \
        l1.u[2] = pack2(v3.x - truncbf(v3.x), v3.y - truncbf(v3.y));          \
        l1.u[3] = pack2(v3.z - truncbf(v3.z), v3.w - truncbf(v3.w));          \
        *(uint4*)(bstage + ((((BUF) * 16 + (SUB) * 4 + 0) * 64 + lane) << 4)) = h0.u4; \
        *(uint4*)(bstage + ((((BUF) * 16 + (SUB) * 4 + 1) * 64 + lane) << 4)) = h1.u4; \
        *(uint4*)(bstage + ((((BUF) * 16 + (SUB) * 4 + 2) * 64 + lane) << 4)) = l0.u4; \
        *(uint4*)(bstage + ((((BUF) * 16 + (SUB) * 4 + 3) * 64 + lane) << 4)) = l1.u4; \
    }

// compute: all 8 waves, 4 subtiles of buffer BUF -> comb[BUF].
// Split-chain MFMA (3+3 by k-half) + tree epilogue + gather reductions.
#define COMPUTE_HALF(BUF)                                                     \
    _Pragma("unroll")                                                         \
    for (int pt = 0; pt < 4; ++pt) {                                          \
        union { uint4 u4; bf16x8 v; } b0, b1, b2, b3;                         \
        b0.u4 = *(const uint4*)(bstage + ((((BUF) * 16 + pt * 4 + 0) * 64 + lane) << 4)); \
        b1.u4 = *(const uint4*)(bstage + ((((BUF) * 16 + pt * 4 + 1) * 64 + lane) << 4)); \
        b2.u4 = *(const uint4*)(bstage + ((((BUF) * 16 + pt * 4 + 2) * 64 + lane) << 4)); \
        b3.u4 = *(const uint4*)(bstage + ((((BUF) * 16 + pt * 4 + 3) * 64 + lane) << 4)); \
        const float x2p = x2s[BUF][pt * 16 + r];                              \
        f32x4 acc[2];                                                         \
        _Pragma("unroll")                                                     \
        for (int ct = 0; ct < 2; ++ct) {                                      \
            f32x4 aA;                                                         \
            aA[0] = x2p + c2r1[ct][0]; aA[1] = x2p + c2r1[ct][1];             \
            aA[2] = x2p + c2r1[ct][2]; aA[3] = x2p + c2r1[ct][3];             \
            f32x4 aB = {0.f, 0.f, 0.f, 0.f};                                  \
            aA = __builtin_amdgcn_mfma_f32_16x16x32_bf16(af[ct][0], b0.v, aA, 0, 0, 0); \
            aB = __builtin_amdgcn_mfma_f32_16x16x32_bf16(af[ct][1], b1.v, aB, 0, 0, 0); \
            aA = __builtin_amdgcn_mfma_f32_16x16x32_bf16(af[ct][2], b0.v, aA, 0, 0, 0); \
            aB = __builtin_amdgcn_mfma_f32_16x16x32_bf16(af[ct][3], b1.v, aB, 0, 0, 0); \
            aA = __builtin_amdgcn_mfma_f32_16x16x32_bf16(af[ct][0], b2.v, aA, 0, 0, 0); \
            aB = __builtin_amdgcn_mfma_f32_16x16x32_bf16(af[ct][1], b3.v, aB, 0, 0, 0); \
            acc[ct] = aA + aB;                                                \
        }                                                                     \
        float swe_c[2], swd_c[2];                                             \
        unsigned bst_c[2];                                                    \
        _Pragma("unroll")                                                     \
        for (int ct = 0; ct < 2; ++ct) {                                      \
            const float u0 = acc[ct][0], u1 = acc[ct][1];                     \
            const float u2 = acc[ct][2], u3 = acc[ct][3];                     \
            const unsigned kb = (unsigned)(w * 32 + ct * 16 + q * 4);         \
            const unsigned p0 = (__float_as_uint(u0) & 0xFFFFFF00u) | kb;     \
            const unsigned p1 = (__float_as_uint(u1) & 0xFFFFFF00u) | (kb + 1); \
            const unsigned p2 = (__float_as_uint(u2) & 0xFFFFFF00u) | (kb + 2); \
            const unsigned p3 = (__float_as_uint(u3) & 0xFFFFFF00u) | (kb + 3); \
            bst_c[ct] = min(min(p0, p1), min(p2, p3));                        \
            const float g0 = exp2f(-ALPHA * __log2f(u0));                     \
            const float g1 = exp2f(-ALPHA * __log2f(u1));                     \
            const float g2 = exp2f(-ALPHA * __log2f(u2));                     \
            const float g3 = exp2f(-ALPHA * __log2f(u3));                     \
            swe_c[ct] = (g0 + g1) + (g2 + g3);                                \
            float t0 = g0 * u0; t0 = fmaf(g1, u1, t0);                        \
            float t1 = g2 * u2; t1 = fmaf(g3, u3, t1);                        \
            swd_c[ct] = t0 + t1;                                              \
        }                                                                     \
        float swe  = swe_c[0] + swe_c[1];                                     \
        float swdu = swd_c[0] + swd_c[1];                                     \
        unsigned best = min(bst_c[0], bst_c[1]);                              \
        swe  = gsum4(swe, s1, s2, s3);                                        \
        swdu = gsum4(swdu, s1, s2, s3);                                       \
        best = gmin4(best, s1, s2, s3);                                       \
        if (q == 0) {                                                         \
            comb_swe[BUF][w][pt * 16 + r]  = swe;                             \
            comb_swd[BUF][w][pt * 16 + r]  = swdu;                            \
            comb_best[BUF][w][pt * 16 + r] = best;                            \
        }                                                                     \
    }

// combine: one wave (64 lanes = 64 points of the half) folds the 8 groups.
#define COMBINE_HALF(BUF, YL)                                                 \
    {                                                                         \
        float SWE = comb_swe[BUF][0][lane], SWD = comb_swd[BUF][0][lane];     \
        unsigned BEST = comb_best[BUF][0][lane];                              \
        _Pragma("unroll")                                                     \
        for (int g = 1; g < 8; ++g) {                                         \
            SWE += comb_swe[BUF][g][lane];                                    \
            SWD += comb_swd[BUF][g][lane];                                    \
            BEST = min(BEST, comb_best[BUF][g][lane]);                        \
        }                                                                     \
        loss_local += SWD / SWE - 1.f;                                        \
        const unsigned bk = BEST & 0xFFu;                                     \
        if (bk < NUM_CLASSES) {                                               \
            atomicAdd(&counts_l[bk * NUM_CLASSES + (YL)], 1u);                \
        }                                                                     \
    }

// 512 threads = 8 waves.  Wave w owns centers [w*32, w*32+32) (M dim) and
// stages points [t*128 + w*16, +16): quad0 (w<4) = even halves (pts 0-63),
// quad1 = odd halves (pts 64-127).  Lane: r = l&15, q = l>>4.
__global__ __launch_bounds__(512, 4) void dist_kernel(
    const float* __restrict__ x,
    const int*   __restrict__ y,
    const float* __restrict__ centers,
    float* __restrict__ loss_acc,
    unsigned int* __restrict__ counts,
    int NT)
{
    __shared__ __align__(16) char bstage[2 * 16 * 64 * 16];   // 32 KB, 2 bufs
    __shared__ float x2s[2][64];
    __shared__ float c2s[256];
    __shared__ float    comb_swe[2][8][64];    // 4 KB
    __shared__ float    comb_swd[2][8][64];    // 4 KB
    __shared__ unsigned comb_best[2][8][64];   // 4 KB
    __shared__ unsigned counts_l[100];

    const int tid  = threadIdx.x;
    const int w    = tid >> 6;
    const int lane = tid & 63;
    const int q    = lane >> 4;
    const int r    = lane & 15;
    const int s1 = r + 16, s2 = r + 32, s3 = r + 48;   // gather partners

    if (tid < 100) counts_l[tid] = 0u;

    // ---- startup: center norms (one center per thread) ----
    if (tid < 256) {
        const float4* crow = (const float4*)(centers + tid * 64);
        float s = 0.f;
#pragma unroll
        for (int j = 0; j < 16; ++j) {
            float4 v = crow[j];
            s = fmaf(v.x, v.x, s); s = fmaf(v.y, v.y, s);
            s = fmaf(v.z, v.z, s); s = fmaf(v.w, v.w, s);
        }
        c2s[tid] = s;
    }

    // ---- startup: this wave's center A-frags, PRE-SCALED by -2 ----
    bf16x8 af[2][4];
#pragma unroll
    for (int ct = 0; ct < 2; ++ct) {
        const int row = w * 32 + ct * 16 + r;
        const float4* C = (const float4*)(centers + (size_t)row * 64);
        float4 v0 = C[q * 2], v1 = C[q * 2 + 1];
        float4 v2 = C[8 + q * 2], v3 = C[9 + q * 2];
        float4 m0 = make_float4(-2.f * v0.x, -2.f * v0.y, -2.f * v0.z, -2.f * v0.w);
        float4 m1 = make_float4(-2.f * v1.x, -2.f * v1.y, -2.f * v1.z, -2.f * v1.w);
        float4 m2 = make_float4(-2.f * v2.x, -2.f * v2.y, -2.f * v2.z, -2.f * v2.w);
        float4 m3 = make_float4(-2.f * v3.x, -2.f * v3.y, -2.f * v3.z, -2.f * v3.w);
        union { bf16x8 v; unsigned u[4]; } h0, h1, l0, l1;
        h0.u[0] = pack2(m0.x, m0.y); h0.u[1] = pack2(m0.z, m0.w);
        h0.u[2] = pack2(m1.x, m1.y); h0.u[3] = pack2(m1.z, m1.w);
        h1.u[0] = pack2(m2.x, m2.y); h1.u[1] = pack2(m2.z, m2.w);
        h1.u[2] = pack2(m3.x, m3.y); h1.u[3] = pack2(m3.z, m3.w);
        l0.u[0] = pack2(m0.x - truncbf(m0.x), m0.y - truncbf(m0.y));
        l0.u[1] = pack2(m0.z - truncbf(m0.z), m0.w - truncbf(m0.w));
        l0.u[2] = pack2(m1.x - truncbf(m1.x), m1.y - truncbf(m1.y));
        l0.u[3] = pack2(m1.z - truncbf(m1.z), m1.w - truncbf(m1.w));
        l1.u[0] = pack2(m2.x - truncbf(m2.x), m2.y - truncbf(m2.y));
        l1.u[1] = pack2(m2.z - truncbf(m2.z), m2.w - truncbf(m2.w));
        l1.u[2] = pack2(m3.x - truncbf(m3.x), m3.y - truncbf(m3.y));
        l1.u[3] = pack2(m3.z - truncbf(m3.z), m3.w - truncbf(m3.w));
        af[ct][0] = h0.v; af[ct][1] = h1.v; af[ct][2] = l0.v; af[ct][3] = l1.v;
    }

    // ---- prefetch tile t0's x rows (every wave: its own 16-pt subtile) ----
    const int G  = gridDim.x;
    const int t0 = blockIdx.x;
    float4 pv0, pv1, pv2, pv3;
    {
        const int row = t0 * 128 + w * 16 + r;
        const float4* X = (const float4*)(x + (size_t)row * 64);
        pv0 = X[q * 2]; pv1 = X[q * 2 + 1];
        pv2 = X[8 + q * 2]; pv3 = X[9 + q * 2];
    }

    // ---- prologue: quad0 stages half(t0,0) into buf0 ----
    if (w < 4) STAGE_HALF(0, w, t0 + G);

    __syncthreads();   // c2s + buf0 + x2s[0] + counts_l visible

    // this lane's 8 center norms + 1: u = (x2 + c2 + 1) + (-2 x.c)
    float c2r1[2][4];
#pragma unroll
    for (int ct = 0; ct < 2; ++ct) {
        float4 v = *(const float4*)(c2s + w * 32 + ct * 16 + q * 4);
        c2r1[ct][0] = v.x + 1.f; c2r1[ct][1] = v.y + 1.f;
        c2r1[ct][2] = v.z + 1.f; c2r1[ct][3] = v.w + 1.f;
    }

    float loss_local = 0.f;
    int have_prev = 0;
    int t = t0;
    for (; t < NT; t += G) {
        // ---- body A: stage half(t,1)[quad1] || compute half(t,0)[all]
        //              || combine half(t-G,1)[wave 0] ----
        int yA = 0;
        if (w == 0 && have_prev) yA = y[(t - G) * 128 + 64 + lane];
        if (w >= 4) STAGE_HALF(1, w - 4, t + G);
        COMPUTE_HALF(0);
        if (w == 0 && have_prev) COMBINE_HALF(1, yA);
        __syncthreads();   // buf1+x2s[1] staged; comb[0] full; comb[1] free

        // ---- body B: stage half(t+G,0)[quad0] || compute half(t,1)[all]
        //              || combine half(t,0)[wave 7] ----
        int yB = 0;
        if (w == 7) yB = y[t * 128 + lane];
        if (w < 4 && (t + G) < NT) STAGE_HALF(0, w, t + 2 * G);
        COMPUTE_HALF(1);
        if (w == 7) COMBINE_HALF(0, yB);
        __syncthreads();   // buf0(next) staged; comb[1] full; comb[0] free

        have_prev = 1;
    }

    // ---- drain: combine the final odd half (t_last,1) ----
    if (w == 0) {
        const int tl = t - G;
        const int yD = y[tl * 128 + 64 + lane];
        COMBINE_HALF(1, yD);
    }

    // loss lives on waves 0 and 7 only
    if (w == 0 || w == 7) {
        float v = loss_local;
#pragma unroll
        for (int o = 32; o > 0; o >>= 1) v += __shfl_down(v, o);
        if (lane == 0) atomicAdd(loss_acc, v);
    }

    __syncthreads();
    if (tid < 100) {
        const unsigned c = counts_l[tid];
        if (c) atomicAdd(&counts[tid], c);
    }
}

// ---------------------------------------------------------------------------
// Finalize: greedy cluster->label assignment, exactly mirroring the reference.
// Counts loaded by 100 parallel threads.
// ---------------------------------------------------------------------------

__global__ void finalize_kernel(
    const float* __restrict__ loss_acc,
    const unsigned int* __restrict__ counts,
    float* __restrict__ out,
    int N)
{
    __shared__ float cs[NUM_CLASSES * NUM_CLASSES];
    __shared__ float ls;
    const int tid = threadIdx.x;
    if (tid < NUM_CLASSES * NUM_CLASSES) cs[tid] = (float)counts[tid];
    if (tid == NUM_CLASSES * NUM_CLASSES) ls = loss_acc[0];
    __syncthreads();
    if (tid == 0) {
        bool used[NUM_CLASSES];
        for (int i = 0; i < NUM_CLASSES; ++i) used[i] = false;

        float correct = 0.f;
        for (int i = 0; i < NUM_CLASSES; ++i) {
            const float* ci = cs + i * NUM_CLASSES;
            float rowsum = 0.f;
            for (int j = 0; j < NUM_CLASSES; ++j) rowsum += ci[j];
            bool has_points = rowsum > 0.f;

            int label = 0;
            float mx = ci[0];
            for (int j = 1; j < NUM_CLASSES; ++j)
                if (ci[j] > mx) { mx = ci[j]; label = j; }

            if (used[label]) {
                float mm = used[0] ? 0.f : ci[0];
                int l2 = 0;
                for (int j = 1; j < NUM_CLASSES; ++j) {
                    float v = used[j] ? 0.f : ci[j];
                    if (v > mm) { mm = v; l2 = j; }
                }
                label = l2;
            }

            if (has_points) {
                correct += ci[label];
                used[label] = true;
            }
        }
        out[0] = ls;
        out[1] = correct / (float)N;
    }
}

// ---------------------------------------------------------------------------

extern "C" void kernel_launch(void* const* d_in, const int* in_sizes, int n_in,
                              void* d_out, int out_size, void* d_ws, size_t ws_size,
                              hipStream_t stream)
{
    const float* x       = (const float*)d_in[0];
    const int*   y       = (const int*)d_in[1];
    const float* centers = (const float*)d_in[2];
    float* out = (float*)d_out;

    const int N  = in_sizes[0] / 64;  // D = 64
    const int NT = N / 128;           // 128-point tiles

    float* loss          = (float*)d_ws;                       // 4 B
    unsigned int* counts = (unsigned int*)((char*)d_ws + 4);   // 400 B

    hipMemsetAsync(d_ws, 0, 512, stream);

    int grid = 1024;   // NT=2048 -> 2 tiles/block; LDS ~48KB -> 3 blocks/CU
    if (grid > NT) grid = NT;
    dist_kernel<<<grid, 512, 0, stream>>>(x, y, centers, loss, counts, NT);

    finalize_kernel<<<1, 128, 0, stream>>>(loss, counts, out, N);
}

// Round 10
// 149.281 us; speedup vs baseline: 1.6701x; 1.0117x over previous
//
#include <hip/hip_runtime.h>

#define ALPHA 0.1f
#define NUM_CLASSES 10

typedef __attribute__((ext_vector_type(8))) short bf16x8;
typedef __attribute__((ext_vector_type(4))) float f32x4;
typedef __attribute__((ext_vector_type(2))) float f32x2;

// ---------------------------------------------------------------------------
// ws layout (bytes):
//   loss  @ 0   : float[1]
//   counts@ 4   : uint[100]
// (zeroed each launch via hipMemsetAsync)
//
// ROUND 20: instruction-count attack on the R17 skeleton.
//   Six scheduling variants (R10/13/15/17/19) all pinned at 69-75us dist:
//   VALUBusy 47% (~33us of issue) is the largest consumer, 3x MFMA.  All
//   prior rounds rearranged WHEN instructions issue; this one reduces HOW
//   MANY, with gfx950-specific ops:
//    i.  pack2 -> single v_perm_b32 (was ~2-3 VALU; x32/tile staging).
//    ii. argmin bit-pack (u&0xFFFFFF00)|kid -> one v_perm_b32 with kid
//        precomputed in 8 persistent VGPRs (was and+or; x8/pt).
//    iii.epilogue acc-init / -ALPHA*log muls / swe adds / swd fmas written
//        as <2..4 x float> vector ops -> v_pk_{add,mul,fma}_f32 (2 fp32
//        per instruction; 32 scalar -> ~16 packed per pt).
//   Numerics: per-lane bit-identical except benign pairwise-sum reorder of
//   swe/swd (R12's nondeterministic atomic order already passed absmax 0).
//   Skeleton/barriers/MFMA/LDS: byte-for-byte R17 (proven 69.5us).
//   Hard rules: launch_bounds(512,4) only; VGPR may grow to ~84 (free under
//   the 3-blocks/CU LDS cap); WRITE_SIZE jump = spill alarm.
// ---------------------------------------------------------------------------

__device__ __forceinline__ unsigned pack2(float a, float b) {
    // (bits(b) & 0xFFFF0000) | (bits(a) >> 16)  ==  one v_perm_b32
    return __builtin_amdgcn_perm(__float_as_uint(b), __float_as_uint(a),
                                 0x07060302u);
}
__device__ __forceinline__ float truncbf(float a) {
    return __uint_as_float(__float_as_uint(a) & 0xFFFF0000u);
}
__device__ __forceinline__ unsigned packkid(float u, unsigned kid) {
    // (bits(u) & 0xFFFFFF00) | kid  ==  one v_perm_b32 (kid < 256)
    return __builtin_amdgcn_perm(__float_as_uint(u), kid, 0x07060500u);
}

// stage: convert this wave's prefetched 16-pt subtile into buffer BUF slot
// SUB; write x2; reload pv with tile TNEXT's rows (if valid).
#define STAGE_HALF(BUF, SUB, TNEXT)                                           \
    {                                                                         \
        float4 v0 = pv0, v1 = pv1, v2 = pv2, v3 = pv3;                        \
        if ((TNEXT) < NT) {                                                   \
            const int row_ = (TNEXT) * 128 + w * 16 + r;                      \
            const float4* X_ = (const float4*)(x + (size_t)row_ * 64);        \
            pv0 = X_[q * 2]; pv1 = X_[q * 2 + 1];                             \
            pv2 = X_[8 + q * 2]; pv3 = X_[9 + q * 2];                         \
        }                                                                     \
        float p = v0.x * v0.x;                                                \
        p = fmaf(v0.y, v0.y, p); p = fmaf(v0.z, v0.z, p); p = fmaf(v0.w, v0.w, p); \
        p = fmaf(v1.x, v1.x, p); p = fmaf(v1.y, v1.y, p); p = fmaf(v1.z, v1.z, p); p = fmaf(v1.w, v1.w, p); \
        p = fmaf(v2.x, v2.x, p); p = fmaf(v2.y, v2.y, p); p = fmaf(v2.z, v2.z, p); p = fmaf(v2.w, v2.w, p); \
        p = fmaf(v3.x, v3.x, p); p = fmaf(v3.y, v3.y, p); p = fmaf(v3.z, v3.z, p); p = fmaf(v3.w, v3.w, p); \
        p += __shfl_xor(p, 16);                                               \
        p += __shfl_xor(p, 32);                                               \
        if (q == 0) x2s[BUF][(SUB) * 16 + r] = p;                             \
        union { bf16x8 v; uint4 u4; unsigned u[4]; } h0, h1, l0, l1;          \
        h0.u[0] = pack2(v0.x, v0.y); h0.u[1] = pack2(v0.z, v0.w);             \
        h0.u[2] = pack2(v1.x, v1.y); h0.u[3] = pack2(v1.z, v1.w);             \
        h1.u[0] = pack2(v2.x, v2.y); h1.u[1] = pack2(v2.z, v2.w);             \
        h1.u[2] = pack2(v3.x, v3.y); h1.u[3] = pack2(v3.z, v3.w);             \
        l0.u[0] = pack2(v0.x - truncbf(v0.x), v0.y - truncbf(v0.y));          \
        l0.u[1] = pack2(v0.z - truncbf(v0.z), v0.w - truncbf(v0.w));          \
        l0.u[2] = pack2(v1.x - truncbf(v1.x), v1.y - truncbf(v1.y));          \
        l0.u[3] = pack2(v1.z - truncbf(v1.z), v1.w - truncbf(v1.w));          \
        l1.u[0] = pack2(v2.x - truncbf(v2.x), v2.y - truncbf(v2.y));          \
        l1.u[1] = pack2(v2.z - truncbf(v2.z), v2.w - truncbf(v2.w));          \
        l1.u[2] = pack2(v3.x - truncbf(v3.x), v3.y - truncbf(v3.y));          \
        l1.u[3] = pack2(v3.z - truncbf(v3.z), v3.w - truncbf(v3.w));          \
        *(uint4*)(bstage + ((((BUF) * 16 + (SUB) * 4 + 0) * 64 + lane) << 4)) = h0.u4; \
        *(uint4*)(bstage + ((((BUF) * 16 + (SUB) * 4 + 1) * 64 + lane) << 4)) = h1.u4; \
        *(uint4*)(bstage + ((((BUF) * 16 + (SUB) * 4 + 2) * 64 + lane) << 4)) = l0.u4; \
        *(uint4*)(bstage + ((((BUF) * 16 + (SUB) * 4 + 3) * 64 + lane) << 4)) = l1.u4; \
    }

// compute: all 8 waves, 4 subtiles of buffer BUF -> comb[BUF].
// R17 MFMA chain; epilogue uses v_perm argmin pack + packed-fp32 math.
#define COMPUTE_HALF(BUF)                                                     \
    _Pragma("unroll")                                                         \
    for (int pt = 0; pt < 4; ++pt) {                                          \
        union { uint4 u4; bf16x8 v; } b0, b1, b2, b3;                         \
        b0.u4 = *(const uint4*)(bstage + ((((BUF) * 16 + pt * 4 + 0) * 64 + lane) << 4)); \
        b1.u4 = *(const uint4*)(bstage + ((((BUF) * 16 + pt * 4 + 1) * 64 + lane) << 4)); \
        b2.u4 = *(const uint4*)(bstage + ((((BUF) * 16 + pt * 4 + 2) * 64 + lane) << 4)); \
        b3.u4 = *(const uint4*)(bstage + ((((BUF) * 16 + pt * 4 + 3) * 64 + lane) << 4)); \
        const float x2p = x2s[BUF][pt * 16 + r];                              \
        const f32x4 xv = {x2p, x2p, x2p, x2p};                                \
        f32x4 acc[2];                                                         \
        _Pragma("unroll")                                                     \
        for (int ct = 0; ct < 2; ++ct) {                                      \
            f32x4 a = xv + c2r1v[ct];          /* v_pk_add_f32 x2 */          \
            a = __builtin_amdgcn_mfma_f32_16x16x32_bf16(af[ct][0], b0.v, a, 0, 0, 0); \
            a = __builtin_amdgcn_mfma_f32_16x16x32_bf16(af[ct][1], b1.v, a, 0, 0, 0); \
            a = __builtin_amdgcn_mfma_f32_16x16x32_bf16(af[ct][2], b0.v, a, 0, 0, 0); \
            a = __builtin_amdgcn_mfma_f32_16x16x32_bf16(af[ct][3], b1.v, a, 0, 0, 0); \
            a = __builtin_amdgcn_mfma_f32_16x16x32_bf16(af[ct][0], b2.v, a, 0, 0, 0); \
            a = __builtin_amdgcn_mfma_f32_16x16x32_bf16(af[ct][1], b3.v, a, 0, 0, 0); \
            acc[ct] = a;                                                      \
        }                                                                     \
        unsigned best = 0xFFFFFFFFu;                                          \
        f32x2 swe2 = {0.f, 0.f}, swd2 = {0.f, 0.f};                           \
        _Pragma("unroll")                                                     \
        for (int ct = 0; ct < 2; ++ct) {                                      \
            const float u0 = acc[ct][0], u1 = acc[ct][1];                     \
            const float u2 = acc[ct][2], u3 = acc[ct][3];                     \
            const unsigned p0 = packkid(u0, kidp[ct][0]);                     \
            const unsigned p1 = packkid(u1, kidp[ct][1]);                     \
            const unsigned p2 = packkid(u2, kidp[ct][2]);                     \
            const unsigned p3 = packkid(u3, kidp[ct][3]);                     \
            best = min(best, min(min(p0, p1), min(p2, p3)));                  \
            f32x2 m01, m23;                                                   \
            m01[0] = __log2f(u0); m01[1] = __log2f(u1);                       \
            m23[0] = __log2f(u2); m23[1] = __log2f(u3);                       \
            const f32x2 na = {-ALPHA, -ALPHA};                                \
            m01 = m01 * na;                    /* v_pk_mul_f32 */             \
            m23 = m23 * na;                                                   \
            f32x2 w01, w23, u01, u23;                                         \
            w01[0] = exp2f(m01[0]); w01[1] = exp2f(m01[1]);                   \
            w23[0] = exp2f(m23[0]); w23[1] = exp2f(m23[1]);                   \
            u01[0] = u0; u01[1] = u1;                                         \
            u23[0] = u2; u23[1] = u3;                                         \
            swe2 = swe2 + (w01 + w23);         /* v_pk_add_f32 x2 */          \
            swd2 = __builtin_elementwise_fma(w01, u01, swd2);                 \
            swd2 = __builtin_elementwise_fma(w23, u23, swd2);                 \
        }                                                                     \
        float swe  = swe2[0] + swe2[1];                                       \
        float swdu = swd2[0] + swd2[1];                                       \
        swe += __shfl_xor(swe, 16); swe += __shfl_xor(swe, 32);               \
        swdu += __shfl_xor(swdu, 16); swdu += __shfl_xor(swdu, 32);           \
        best = min(best, (unsigned)__shfl_xor((int)best, 16));                \
        best = min(best, (unsigned)__shfl_xor((int)best, 32));                \
        if (q == 0) {                                                         \
            comb_swe[BUF][w][pt * 16 + r]  = swe;                             \
            comb_swd[BUF][w][pt * 16 + r]  = swdu;                            \
            comb_best[BUF][w][pt * 16 + r] = best;                            \
        }                                                                     \
    }

// combine: one wave (64 lanes = 64 points of the half) folds the 8 groups.
#define COMBINE_HALF(BUF, YL)                                                 \
    {                                                                         \
        float SWE = comb_swe[BUF][0][lane], SWD = comb_swd[BUF][0][lane];     \
        unsigned BEST = comb_best[BUF][0][lane];                              \
        _Pragma("unroll")                                                     \
        for (int g = 1; g < 8; ++g) {                                         \
            SWE += comb_swe[BUF][g][lane];                                    \
            SWD += comb_swd[BUF][g][lane];                                    \
            BEST = min(BEST, comb_best[BUF][g][lane]);                        \
        }                                                                     \
        loss_local += SWD / SWE - 1.f;                                        \
        const unsigned bk = BEST & 0xFFu;                                     \
        if (bk < NUM_CLASSES) {                                               \
            atomicAdd(&counts_l[bk * NUM_CLASSES + (YL)], 1u);                \
        }                                                                     \
    }

// 512 threads = 8 waves.  Wave w owns centers [w*32, w*32+32) (M dim) and
// stages points [t*128 + w*16, +16): quad0 (w<4) = even halves (pts 0-63),
// quad1 = odd halves (pts 64-127).  Lane: r = l&15, q = l>>4.
__global__ __launch_bounds__(512, 4) void dist_kernel(
    const float* __restrict__ x,
    const int*   __restrict__ y,
    const float* __restrict__ centers,
    float* __restrict__ loss_acc,
    unsigned int* __restrict__ counts,
    int NT)
{
    __shared__ __align__(16) char bstage[2 * 16 * 64 * 16];   // 32 KB, 2 bufs
    __shared__ float x2s[2][64];
    __shared__ float c2s[256];
    __shared__ float    comb_swe[2][8][64];    // 4 KB
    __shared__ float    comb_swd[2][8][64];    // 4 KB
    __shared__ unsigned comb_best[2][8][64];   // 4 KB
    __shared__ unsigned counts_l[100];

    const int tid  = threadIdx.x;
    const int w    = tid >> 6;
    const int lane = tid & 63;
    const int q    = lane >> 4;
    const int r    = lane & 15;

    if (tid < 100) counts_l[tid] = 0u;

    // ---- startup: center norms (one center per thread) ----
    if (tid < 256) {
        const float4* crow = (const float4*)(centers + tid * 64);
        float s = 0.f;
#pragma unroll
        for (int j = 0; j < 16; ++j) {
            float4 v = crow[j];
            s = fmaf(v.x, v.x, s); s = fmaf(v.y, v.y, s);
            s = fmaf(v.z, v.z, s); s = fmaf(v.w, v.w, s);
        }
        c2s[tid] = s;
    }

    // ---- startup: this wave's center A-frags, PRE-SCALED by -2 ----
    bf16x8 af[2][4];
#pragma unroll
    for (int ct = 0; ct < 2; ++ct) {
        const int row = w * 32 + ct * 16 + r;
        const float4* C = (const float4*)(centers + (size_t)row * 64);
        float4 v0 = C[q * 2], v1 = C[q * 2 + 1];
        float4 v2 = C[8 + q * 2], v3 = C[9 + q * 2];
        float4 m0 = make_float4(-2.f * v0.x, -2.f * v0.y, -2.f * v0.z, -2.f * v0.w);
        float4 m1 = make_float4(-2.f * v1.x, -2.f * v1.y, -2.f * v1.z, -2.f * v1.w);
        float4 m2 = make_float4(-2.f * v2.x, -2.f * v2.y, -2.f * v2.z, -2.f * v2.w);
        float4 m3 = make_float4(-2.f * v3.x, -2.f * v3.y, -2.f * v3.z, -2.f * v3.w);
        union { bf16x8 v; unsigned u[4]; } h0, h1, l0, l1;
        h0.u[0] = pack2(m0.x, m0.y); h0.u[1] = pack2(m0.z, m0.w);
        h0.u[2] = pack2(m1.x, m1.y); h0.u[3] = pack2(m1.z, m1.w);
        h1.u[0] = pack2(m2.x, m2.y); h1.u[1] = pack2(m2.z, m2.w);
        h1.u[2] = pack2(m3.x, m3.y); h1.u[3] = pack2(m3.z, m3.w);
        l0.u[0] = pack2(m0.x - truncbf(m0.x), m0.y - truncbf(m0.y));
        l0.u[1] = pack2(m0.z - truncbf(m0.z), m0.w - truncbf(m0.w));
        l0.u[2] = pack2(m1.x - truncbf(m1.x), m1.y - truncbf(m1.y));
        l0.u[3] = pack2(m1.z - truncbf(m1.z), m1.w - truncbf(m1.w));
        l1.u[0] = pack2(m2.x - truncbf(m2.x), m2.y - truncbf(m2.y));
        l1.u[1] = pack2(m2.z - truncbf(m2.z), m2.w - truncbf(m2.w));
        l1.u[2] = pack2(m3.x - truncbf(m3.x), m3.y - truncbf(m3.y));
        l1.u[3] = pack2(m3.z - truncbf(m3.z), m3.w - truncbf(m3.w));
        af[ct][0] = h0.v; af[ct][1] = h1.v; af[ct][2] = l0.v; af[ct][3] = l1.v;
    }

    // ---- startup: per-lane argmin kid bytes (persistent, for v_perm) ----
    unsigned kidp[2][4];
#pragma unroll
    for (int ct = 0; ct < 2; ++ct)
#pragma unroll
        for (int reg = 0; reg < 4; ++reg)
            kidp[ct][reg] = (unsigned)(w * 32 + ct * 16 + q * 4 + reg);

    // ---- prefetch tile t0's x rows (every wave: its own 16-pt subtile) ----
    const int G  = gridDim.x;
    const int t0 = blockIdx.x;
    float4 pv0, pv1, pv2, pv3;
    {
        const int row = t0 * 128 + w * 16 + r;
        const float4* X = (const float4*)(x + (size_t)row * 64);
        pv0 = X[q * 2]; pv1 = X[q * 2 + 1];
        pv2 = X[8 + q * 2]; pv3 = X[9 + q * 2];
    }

    // ---- prologue: quad0 stages half(t0,0) into buf0 ----
    if (w < 4) STAGE_HALF(0, w, t0 + G);

    __syncthreads();   // c2s + buf0 + x2s[0] + counts_l visible

    // this lane's 8 center norms + 1 (f32x4 for packed acc-init)
    f32x4 c2r1v[2];
#pragma unroll
    for (int ct = 0; ct < 2; ++ct) {
        const float4 v = *(const float4*)(c2s + w * 32 + ct * 16 + q * 4);
        f32x4 t; t[0] = v.x + 1.f; t[1] = v.y + 1.f;
        t[2] = v.z + 1.f; t[3] = v.w + 1.f;
        c2r1v[ct] = t;
    }

    float loss_local = 0.f;
    int have_prev = 0;
    int t = t0;
    for (; t < NT; t += G) {
        // ---- body A: stage half(t,1)[quad1] || compute half(t,0)[all]
        //              || combine half(t-G,1)[wave 0] ----
        int yA = 0;
        if (w == 0 && have_prev) yA = y[(t - G) * 128 + 64 + lane];
        if (w >= 4) STAGE_HALF(1, w - 4, t + G);
        COMPUTE_HALF(0);
        if (w == 0 && have_prev) COMBINE_HALF(1, yA);
        __syncthreads();   // buf1+x2s[1] staged; comb[0] full; comb[1] free

        // ---- body B: stage half(t+G,0)[quad0] || compute half(t,1)[all]
        //              || combine half(t,0)[wave 7] ----
        int yB = 0;
        if (w == 7) yB = y[t * 128 + lane];
        if (w < 4 && (t + G) < NT) STAGE_HALF(0, w, t + 2 * G);
        COMPUTE_HALF(1);
        if (w == 7) COMBINE_HALF(0, yB);
        __syncthreads();   // buf0(next) staged; comb[1] full; comb[0] free

        have_prev = 1;
    }

    // ---- drain: combine the final odd half (t_last,1) ----
    if (w == 0) {
        const int tl = t - G;
        const int yD = y[tl * 128 + 64 + lane];
        COMBINE_HALF(1, yD);
    }

    // loss lives on waves 0 and 7 only
    if (w == 0 || w == 7) {
        float v = loss_local;
#pragma unroll
        for (int o = 32; o > 0; o >>= 1) v += __shfl_down(v, o);
        if (lane == 0) atomicAdd(loss_acc, v);
    }

    __syncthreads();
    if (tid < 100) {
        const unsigned c = counts_l[tid];
        if (c) atomicAdd(&counts[tid], c);
    }
}

// ---------------------------------------------------------------------------
// Finalize: greedy cluster->label assignment, exactly mirroring the reference.
// Counts loaded by 100 parallel threads.
// ---------------------------------------------------------------------------

__global__ void finalize_kernel(
    const float* __restrict__ loss_acc,
    const unsigned int* __restrict__ counts,
    float* __restrict__ out,
    int N)
{
    __shared__ float cs[NUM_CLASSES * NUM_CLASSES];
    __shared__ float ls;
    const int tid = threadIdx.x;
    if (tid < NUM_CLASSES * NUM_CLASSES) cs[tid] = (float)counts[tid];
    if (tid == NUM_CLASSES * NUM_CLASSES) ls = loss_acc[0];
    __syncthreads();
    if (tid == 0) {
        bool used[NUM_CLASSES];
        for (int i = 0; i < NUM_CLASSES; ++i) used[i] = false;

        float correct = 0.f;
        for (int i = 0; i < NUM_CLASSES; ++i) {
            const float* ci = cs + i * NUM_CLASSES;
            float rowsum = 0.f;
            for (int j = 0; j < NUM_CLASSES; ++j) rowsum += ci[j];
            bool has_points = rowsum > 0.f;

            int label = 0;
            float mx = ci[0];
            for (int j = 1; j < NUM_CLASSES; ++j)
                if (ci[j] > mx) { mx = ci[j]; label = j; }

            if (used[label]) {
                float mm = used[0] ? 0.f : ci[0];
                int l2 = 0;
                for (int j = 1; j < NUM_CLASSES; ++j) {
                    float v = used[j] ? 0.f : ci[j];
                    if (v > mm) { mm = v; l2 = j; }
                }
                label = l2;
            }

            if (has_points) {
                correct += ci[label];
                used[label] = true;
            }
        }
        out[0] = ls;
        out[1] = correct / (float)N;
    }
}

// ---------------------------------------------------------------------------

extern "C" void kernel_launch(void* const* d_in, const int* in_sizes, int n_in,
                              void* d_out, int out_size, void* d_ws, size_t ws_size,
                              hipStream_t stream)
{
    const float* x       = (const float*)d_in[0];
    const int*   y       = (const int*)d_in[1];
    const float* centers = (const float*)d_in[2];
    float* out = (float*)d_out;

    const int N  = in_sizes[0] / 64;  // D = 64
    const int NT = N / 128;           // 128-point tiles

    float* loss          = (float*)d_ws;                       // 4 B
    unsigned int* counts = (unsigned int*)((char*)d_ws + 4);   // 400 B

    hipMemsetAsync(d_ws, 0, 512, stream);

    int grid = 1024;   // NT=2048 -> 2 tiles/block; LDS ~48KB -> 3 blocks/CU
    if (grid > NT) grid = NT;
    dist_kernel<<<grid, 512, 0, stream>>>(x, y, centers, loss, counts, NT);

    finalize_kernel<<<1, 128, 0, stream>>>(loss, counts, out, N);
}

// Round 11
// 146.622 us; speedup vs baseline: 1.7004x; 1.0181x over previous
//
#include <hip/hip_runtime.h>

#define ALPHA 0.1f
#define NUM_CLASSES 10

typedef __attribute__((ext_vector_type(8))) short bf16x8;
typedef __attribute__((ext_vector_type(4))) float f32x4;
typedef __attribute__((ext_vector_type(2))) float f32x2;

// ---------------------------------------------------------------------------
// ws layout (bytes):
//   loss  @ 0   : float[1]
//   counts@ 4   : uint[100]
// (zeroed each launch via hipMemsetAsync)
//
// ROUND 21: dispatch-shape fix on the byte-identical R20 kernel.
//   R20 showed VALUBusy 47->44.5% with dur unchanged -> not VALU-bound.
//   The one untested confounder: grid=1024 at 3-blocks/CU residency means
//   every CU runs 3 blocks (24 waves), then the 4th block ALONE (8 waves)
//   for a full S+2T lifetime -- half-throughput tail for a latency-limited
//   kernel, plus a 4th per-block startup.  OccupancyPercent ~33% (vs 75%
//   static) is consistent with this skinny tail.
//   Fix: grid = 768 = exactly 3 blocks/CU, all resident at t=0; blocks
//   grid-stride 2-3 tiles.  Everything else byte-identical to R20
//   (v_perm packs, packed-fp32 epilogue, ping-pong dbuf, 64-ish VGPR).
//   Predict: dist ~56-63us if tail theory holds; neutral -> declare
//   ceiling at R20.
// ---------------------------------------------------------------------------

__device__ __forceinline__ unsigned pack2(float a, float b) {
    // (bits(b) & 0xFFFF0000) | (bits(a) >> 16)  ==  one v_perm_b32
    return __builtin_amdgcn_perm(__float_as_uint(b), __float_as_uint(a),
                                 0x07060302u);
}
__device__ __forceinline__ float truncbf(float a) {
    return __uint_as_float(__float_as_uint(a) & 0xFFFF0000u);
}
__device__ __forceinline__ unsigned packkid(float u, unsigned kid) {
    // (bits(u) & 0xFFFFFF00) | kid  ==  one v_perm_b32 (kid < 256)
    return __builtin_amdgcn_perm(__float_as_uint(u), kid, 0x07060500u);
}

// stage: convert this wave's prefetched 16-pt subtile into buffer BUF slot
// SUB; write x2; reload pv with tile TNEXT's rows (if valid).
#define STAGE_HALF(BUF, SUB, TNEXT)                                           \
    {                                                                         \
        float4 v0 = pv0, v1 = pv1, v2 = pv2, v3 = pv3;                        \
        if ((TNEXT) < NT) {                                                   \
            const int row_ = (TNEXT) * 128 + w * 16 + r;                      \
            const float4* X_ = (const float4*)(x + (size_t)row_ * 64);        \
            pv0 = X_[q * 2]; pv1 = X_[q * 2 + 1];                             \
            pv2 = X_[8 + q * 2]; pv3 = X_[9 + q * 2];                         \
        }                                                                     \
        float p = v0.x * v0.x;                                                \
        p = fmaf(v0.y, v0.y, p); p = fmaf(v0.z, v0.z, p); p = fmaf(v0.w, v0.w, p); \
        p = fmaf(v1.x, v1.x, p); p = fmaf(v1.y, v1.y, p); p = fmaf(v1.z, v1.z, p); p = fmaf(v1.w, v1.w, p); \
        p = fmaf(v2.x, v2.x, p); p = fmaf(v2.y, v2.y, p); p = fmaf(v2.z, v2.z, p); p = fmaf(v2.w, v2.w, p); \
        p = fmaf(v3.x, v3.x, p); p = fmaf(v3.y, v3.y, p); p = fmaf(v3.z, v3.z, p); p = fmaf(v3.w, v3.w, p); \
        p += __shfl_xor(p, 16);                                               \
        p += __shfl_xor(p, 32);                                               \
        if (q == 0) x2s[BUF][(SUB) * 16 + r] = p;                             \
        union { bf16x8 v; uint4 u4; unsigned u[4]; } h0, h1, l0, l1;          \
        h0.u[0] = pack2(v0.x, v0.y); h0.u[1] = pack2(v0.z, v0.w);             \
        h0.u[2] = pack2(v1.x, v1.y); h0.u[3] = pack2(v1.z, v1.w);             \
        h1.u[0] = pack2(v2.x, v2.y); h1.u[1] = pack2(v2.z, v2.w);             \
        h1.u[2] = pack2(v3.x, v3.y); h1.u[3] = pack2(v3.z, v3.w);             \
        l0.u[0] = pack2(v0.x - truncbf(v0.x), v0.y - truncbf(v0.y));          \
        l0.u[1] = pack2(v0.z - truncbf(v0.z), v0.w - truncbf(v0.w));          \
        l0.u[2] = pack2(v1.x - truncbf(v1.x), v1.y - truncbf(v1.y));          \
        l0.u[3] = pack2(v1.z - truncbf(v1.z), v1.w - truncbf(v1.w));          \
        l1.u[0] = pack2(v2.x - truncbf(v2.x), v2.y - truncbf(v2.y));          \
        l1.u[1] = pack2(v2.z - truncbf(v2.z), v2.w - truncbf(v2.w));          \
        l1.u[2] = pack2(v3.x - truncbf(v3.x), v3.y - truncbf(v3.y));          \
        l1.u[3] = pack2(v3.z - truncbf(v3.z), v3.w - truncbf(v3.w));          \
        *(uint4*)(bstage + ((((BUF) * 16 + (SUB) * 4 + 0) * 64 + lane) << 4)) = h0.u4; \
        *(uint4*)(bstage + ((((BUF) * 16 + (SUB) * 4 + 1) * 64 + lane) << 4)) = h1.u4; \
        *(uint4*)(bstage + ((((BUF) * 16 + (SUB) * 4 + 2) * 64 + lane) << 4)) = l0.u4; \
        *(uint4*)(bstage + ((((BUF) * 16 + (SUB) * 4 + 3) * 64 + lane) << 4)) = l1.u4; \
    }

// compute: all 8 waves, 4 subtiles of buffer BUF -> comb[BUF].
// R17 MFMA chain; epilogue uses v_perm argmin pack + packed-fp32 math.
#define COMPUTE_HALF(BUF)                                                     \
    _Pragma("unroll")                                                         \
    for (int pt = 0; pt < 4; ++pt) {                                          \
        union { uint4 u4; bf16x8 v; } b0, b1, b2, b3;                         \
        b0.u4 = *(const uint4*)(bstage + ((((BUF) * 16 + pt * 4 + 0) * 64 + lane) << 4)); \
        b1.u4 = *(const uint4*)(bstage + ((((BUF) * 16 + pt * 4 + 1) * 64 + lane) << 4)); \
        b2.u4 = *(const uint4*)(bstage + ((((BUF) * 16 + pt * 4 + 2) * 64 + lane) << 4)); \
        b3.u4 = *(const uint4*)(bstage + ((((BUF) * 16 + pt * 4 + 3) * 64 + lane) << 4)); \
        const float x2p = x2s[BUF][pt * 16 + r];                              \
        const f32x4 xv = {x2p, x2p, x2p, x2p};                                \
        f32x4 acc[2];                                                         \
        _Pragma("unroll")                                                     \
        for (int ct = 0; ct < 2; ++ct) {                                      \
            f32x4 a = xv + c2r1v[ct];          /* v_pk_add_f32 x2 */          \
            a = __builtin_amdgcn_mfma_f32_16x16x32_bf16(af[ct][0], b0.v, a, 0, 0, 0); \
            a = __builtin_amdgcn_mfma_f32_16x16x32_bf16(af[ct][1], b1.v, a, 0, 0, 0); \
            a = __builtin_amdgcn_mfma_f32_16x16x32_bf16(af[ct][2], b0.v, a, 0, 0, 0); \
            a = __builtin_amdgcn_mfma_f32_16x16x32_bf16(af[ct][3], b1.v, a, 0, 0, 0); \
            a = __builtin_amdgcn_mfma_f32_16x16x32_bf16(af[ct][0], b2.v, a, 0, 0, 0); \
            a = __builtin_amdgcn_mfma_f32_16x16x32_bf16(af[ct][1], b3.v, a, 0, 0, 0); \
            acc[ct] = a;                                                      \
        }                                                                     \
        unsigned best = 0xFFFFFFFFu;                                          \
        f32x2 swe2 = {0.f, 0.f}, swd2 = {0.f, 0.f};                           \
        _Pragma("unroll")                                                     \
        for (int ct = 0; ct < 2; ++ct) {                                      \
            const float u0 = acc[ct][0], u1 = acc[ct][1];                     \
            const float u2 = acc[ct][2], u3 = acc[ct][3];                     \
            const unsigned p0 = packkid(u0, kidp[ct][0]);                     \
            const unsigned p1 = packkid(u1, kidp[ct][1]);                     \
            const unsigned p2 = packkid(u2, kidp[ct][2]);                     \
            const unsigned p3 = packkid(u3, kidp[ct][3]);                     \
            best = min(best, min(min(p0, p1), min(p2, p3)));                  \
            f32x2 m01, m23;                                                   \
            m01[0] = __log2f(u0); m01[1] = __log2f(u1);                       \
            m23[0] = __log2f(u2); m23[1] = __log2f(u3);                       \
            const f32x2 na = {-ALPHA, -ALPHA};                                \
            m01 = m01 * na;                    /* v_pk_mul_f32 */             \
            m23 = m23 * na;                                                   \
            f32x2 w01, w23, u01, u23;                                         \
            w01[0] = exp2f(m01[0]); w01[1] = exp2f(m01[1]);                   \
            w23[0] = exp2f(m23[0]); w23[1] = exp2f(m23[1]);                   \
            u01[0] = u0; u01[1] = u1;                                         \
            u23[0] = u2; u23[1] = u3;                                         \
            swe2 = swe2 + (w01 + w23);         /* v_pk_add_f32 x2 */          \
            swd2 = __builtin_elementwise_fma(w01, u01, swd2);                 \
            swd2 = __builtin_elementwise_fma(w23, u23, swd2);                 \
        }                                                                     \
        float swe  = swe2[0] + swe2[1];                                       \
        float swdu = swd2[0] + swd2[1];                                       \
        swe += __shfl_xor(swe, 16); swe += __shfl_xor(swe, 32);               \
        swdu += __shfl_xor(swdu, 16); swdu += __shfl_xor(swdu, 32);           \
        best = min(best, (unsigned)__shfl_xor((int)best, 16));                \
        best = min(best, (unsigned)__shfl_xor((int)best, 32));                \
        if (q == 0) {                                                         \
            comb_swe[BUF][w][pt * 16 + r]  = swe;                             \
            comb_swd[BUF][w][pt * 16 + r]  = swdu;                            \
            comb_best[BUF][w][pt * 16 + r] = best;                            \
        }                                                                     \
    }

// combine: one wave (64 lanes = 64 points of the half) folds the 8 groups.
#define COMBINE_HALF(BUF, YL)                                                 \
    {                                                                         \
        float SWE = comb_swe[BUF][0][lane], SWD = comb_swd[BUF][0][lane];     \
        unsigned BEST = comb_best[BUF][0][lane];                              \
        _Pragma("unroll")                                                     \
        for (int g = 1; g < 8; ++g) {                                         \
            SWE += comb_swe[BUF][g][lane];                                    \
            SWD += comb_swd[BUF][g][lane];                                    \
            BEST = min(BEST, comb_best[BUF][g][lane]);                        \
        }                                                                     \
        loss_local += SWD / SWE - 1.f;                                        \
        const unsigned bk = BEST & 0xFFu;                                     \
        if (bk < NUM_CLASSES) {                                               \
            atomicAdd(&counts_l[bk * NUM_CLASSES + (YL)], 1u);                \
        }                                                                     \
    }

// 512 threads = 8 waves.  Wave w owns centers [w*32, w*32+32) (M dim) and
// stages points [t*128 + w*16, +16): quad0 (w<4) = even halves (pts 0-63),
// quad1 = odd halves (pts 64-127).  Lane: r = l&15, q = l>>4.
__global__ __launch_bounds__(512, 4) void dist_kernel(
    const float* __restrict__ x,
    const int*   __restrict__ y,
    const float* __restrict__ centers,
    float* __restrict__ loss_acc,
    unsigned int* __restrict__ counts,
    int NT)
{
    __shared__ __align__(16) char bstage[2 * 16 * 64 * 16];   // 32 KB, 2 bufs
    __shared__ float x2s[2][64];
    __shared__ float c2s[256];
    __shared__ float    comb_swe[2][8][64];    // 4 KB
    __shared__ float    comb_swd[2][8][64];    // 4 KB
    __shared__ unsigned comb_best[2][8][64];   // 4 KB
    __shared__ unsigned counts_l[100];

    const int tid  = threadIdx.x;
    const int w    = tid >> 6;
    const int lane = tid & 63;
    const int q    = lane >> 4;
    const int r    = lane & 15;

    if (tid < 100) counts_l[tid] = 0u;

    // ---- startup: center norms (one center per thread) ----
    if (tid < 256) {
        const float4* crow = (const float4*)(centers + tid * 64);
        float s = 0.f;
#pragma unroll
        for (int j = 0; j < 16; ++j) {
            float4 v = crow[j];
            s = fmaf(v.x, v.x, s); s = fmaf(v.y, v.y, s);
            s = fmaf(v.z, v.z, s); s = fmaf(v.w, v.w, s);
        }
        c2s[tid] = s;
    }

    // ---- startup: this wave's center A-frags, PRE-SCALED by -2 ----
    bf16x8 af[2][4];
#pragma unroll
    for (int ct = 0; ct < 2; ++ct) {
        const int row = w * 32 + ct * 16 + r;
        const float4* C = (const float4*)(centers + (size_t)row * 64);
        float4 v0 = C[q * 2], v1 = C[q * 2 + 1];
        float4 v2 = C[8 + q * 2], v3 = C[9 + q * 2];
        float4 m0 = make_float4(-2.f * v0.x, -2.f * v0.y, -2.f * v0.z, -2.f * v0.w);
        float4 m1 = make_float4(-2.f * v1.x, -2.f * v1.y, -2.f * v1.z, -2.f * v1.w);
        float4 m2 = make_float4(-2.f * v2.x, -2.f * v2.y, -2.f * v2.z, -2.f * v2.w);
        float4 m3 = make_float4(-2.f * v3.x, -2.f * v3.y, -2.f * v3.z, -2.f * v3.w);
        union { bf16x8 v; unsigned u[4]; } h0, h1, l0, l1;
        h0.u[0] = pack2(m0.x, m0.y); h0.u[1] = pack2(m0.z, m0.w);
        h0.u[2] = pack2(m1.x, m1.y); h0.u[3] = pack2(m1.z, m1.w);
        h1.u[0] = pack2(m2.x, m2.y); h1.u[1] = pack2(m2.z, m2.w);
        h1.u[2] = pack2(m3.x, m3.y); h1.u[3] = pack2(m3.z, m3.w);
        l0.u[0] = pack2(m0.x - truncbf(m0.x), m0.y - truncbf(m0.y));
        l0.u[1] = pack2(m0.z - truncbf(m0.z), m0.w - truncbf(m0.w));
        l0.u[2] = pack2(m1.x - truncbf(m1.x), m1.y - truncbf(m1.y));
        l0.u[3] = pack2(m1.z - truncbf(m1.z), m1.w - truncbf(m1.w));
        l1.u[0] = pack2(m2.x - truncbf(m2.x), m2.y - truncbf(m2.y));
        l1.u[1] = pack2(m2.z - truncbf(m2.z), m2.w - truncbf(m2.w));
        l1.u[2] = pack2(m3.x - truncbf(m3.x), m3.y - truncbf(m3.y));
        l1.u[3] = pack2(m3.z - truncbf(m3.z), m3.w - truncbf(m3.w));
        af[ct][0] = h0.v; af[ct][1] = h1.v; af[ct][2] = l0.v; af[ct][3] = l1.v;
    }

    // ---- startup: per-lane argmin kid bytes (persistent, for v_perm) ----
    unsigned kidp[2][4];
#pragma unroll
    for (int ct = 0; ct < 2; ++ct)
#pragma unroll
        for (int reg = 0; reg < 4; ++reg)
            kidp[ct][reg] = (unsigned)(w * 32 + ct * 16 + q * 4 + reg);

    // ---- prefetch tile t0's x rows (every wave: its own 16-pt subtile) ----
    const int G  = gridDim.x;
    const int t0 = blockIdx.x;
    float4 pv0, pv1, pv2, pv3;
    {
        const int row = t0 * 128 + w * 16 + r;
        const float4* X = (const float4*)(x + (size_t)row * 64);
        pv0 = X[q * 2]; pv1 = X[q * 2 + 1];
        pv2 = X[8 + q * 2]; pv3 = X[9 + q * 2];
    }

    // ---- prologue: quad0 stages half(t0,0) into buf0 ----
    if (w < 4) STAGE_HALF(0, w, t0 + G);

    __syncthreads();   // c2s + buf0 + x2s[0] + counts_l visible

    // this lane's 8 center norms + 1 (f32x4 for packed acc-init)
    f32x4 c2r1v[2];
#pragma unroll
    for (int ct = 0; ct < 2; ++ct) {
        const float4 v = *(const float4*)(c2s + w * 32 + ct * 16 + q * 4);
        f32x4 t; t[0] = v.x + 1.f; t[1] = v.y + 1.f;
        t[2] = v.z + 1.f; t[3] = v.w + 1.f;
        c2r1v[ct] = t;
    }

    float loss_local = 0.f;
    int have_prev = 0;
    int t = t0;
    for (; t < NT; t += G) {
        // ---- body A: stage half(t,1)[quad1] || compute half(t,0)[all]
        //              || combine half(t-G,1)[wave 0] ----
        int yA = 0;
        if (w == 0 && have_prev) yA = y[(t - G) * 128 + 64 + lane];
        if (w >= 4) STAGE_HALF(1, w - 4, t + G);
        COMPUTE_HALF(0);
        if (w == 0 && have_prev) COMBINE_HALF(1, yA);
        __syncthreads();   // buf1+x2s[1] staged; comb[0] full; comb[1] free

        // ---- body B: stage half(t+G,0)[quad0] || compute half(t,1)[all]
        //              || combine half(t,0)[wave 7] ----
        int yB = 0;
        if (w == 7) yB = y[t * 128 + lane];
        if (w < 4 && (t + G) < NT) STAGE_HALF(0, w, t + 2 * G);
        COMPUTE_HALF(1);
        if (w == 7) COMBINE_HALF(0, yB);
        __syncthreads();   // buf0(next) staged; comb[1] full; comb[0] free

        have_prev = 1;
    }

    // ---- drain: combine the final odd half (t_last,1) ----
    if (w == 0) {
        const int tl = t - G;
        const int yD = y[tl * 128 + 64 + lane];
        COMBINE_HALF(1, yD);
    }

    // loss lives on waves 0 and 7 only
    if (w == 0 || w == 7) {
        float v = loss_local;
#pragma unroll
        for (int o = 32; o > 0; o >>= 1) v += __shfl_down(v, o);
        if (lane == 0) atomicAdd(loss_acc, v);
    }

    __syncthreads();
    if (tid < 100) {
        const unsigned c = counts_l[tid];
        if (c) atomicAdd(&counts[tid], c);
    }
}

// ---------------------------------------------------------------------------
// Finalize: greedy cluster->label assignment, exactly mirroring the reference.
// Counts loaded by 100 parallel threads.
// ---------------------------------------------------------------------------

__global__ void finalize_kernel(
    const float* __restrict__ loss_acc,
    const unsigned int* __restrict__ counts,
    float* __restrict__ out,
    int N)
{
    __shared__ float cs[NUM_CLASSES * NUM_CLASSES];
    __shared__ float ls;
    const int tid = threadIdx.x;
    if (tid < NUM_CLASSES * NUM_CLASSES) cs[tid] = (float)counts[tid];
    if (tid == NUM_CLASSES * NUM_CLASSES) ls = loss_acc[0];
    __syncthreads();
    if (tid == 0) {
        bool used[NUM_CLASSES];
        for (int i = 0; i < NUM_CLASSES; ++i) used[i] = false;

        float correct = 0.f;
        for (int i = 0; i < NUM_CLASSES; ++i) {
            const float* ci = cs + i * NUM_CLASSES;
            float rowsum = 0.f;
            for (int j = 0; j < NUM_CLASSES; ++j) rowsum += ci[j];
            bool has_points = rowsum > 0.f;

            int label = 0;
            float mx = ci[0];
            for (int j = 1; j < NUM_CLASSES; ++j)
                if (ci[j] > mx) { mx = ci[j]; label = j; }

            if (used[label]) {
                float mm = used[0] ? 0.f : ci[0];
                int l2 = 0;
                for (int j = 1; j < NUM_CLASSES; ++j) {
                    float v = used[j] ? 0.f : ci[j];
                    if (v > mm) { mm = v; l2 = j; }
                }
                label = l2;
            }

            if (has_points) {
                correct += ci[label];
                used[label] = true;
            }
        }
        out[0] = ls;
        out[1] = correct / (float)N;
    }
}

// ---------------------------------------------------------------------------

extern "C" void kernel_launch(void* const* d_in, const int* in_sizes, int n_in,
                              void* d_out, int out_size, void* d_ws, size_t ws_size,
                              hipStream_t stream)
{
    const float* x       = (const float*)d_in[0];
    const int*   y       = (const int*)d_in[1];
    const float* centers = (const float*)d_in[2];
    float* out = (float*)d_out;

    const int N  = in_sizes[0] / 64;  // D = 64
    const int NT = N / 128;           // 128-point tiles

    float* loss          = (float*)d_ws;                       // 4 B
    unsigned int* counts = (unsigned int*)((char*)d_ws + 4);   // 400 B

    hipMemsetAsync(d_ws, 0, 512, stream);

    // grid = 768 = exactly 3 blocks/CU (47KB LDS), ALL resident at t=0.
    // grid=1024 ran a 4th block per CU alone (8 waves) after round 1 --
    // a half-throughput tail for this latency-limited kernel, plus a 4th
    // per-block startup.  Blocks grid-stride 2-3 tiles each.
    int grid = 768;
    if (grid > NT) grid = NT;
    dist_kernel<<<grid, 512, 0, stream>>>(x, y, centers, loss, counts, NT);

    finalize_kernel<<<1, 128, 0, stream>>>(loss, counts, out, N);
}